// Round 9
// baseline (578.744 us; speedup 1.0000x reference)
//
#include <hip/hip_runtime.h>
#include <hip/hip_fp16.h>

#define N_NODES 100000
#define E_EDGES 3200000
#define IN_F 128
#define ATT 128
#define HEADS 8
#define DK 16
#define SLOPE 0.2f
#define NH (N_NODES * HEADS)   // 800000

// Binning parameters  (R9: slots = NS*NH halved via NS 8->4; grid shape kept
// at 1792 blocks via NBINS 224->448, CHUNK 448->224; per-edge work unchanged)
#define CHUNK 224
#define NBINS 448                 // 448*224 = 100352 >= N
#define NS 4                      // splits per bin (grid.y) == private denom copies
#define HB 512                    // hist/scatter blocks
#define EPB 6272                  // edges per hist/scatter block (mult of 4; 512*6272 >= E)

// load a row of 8 halfs (16 B, ONE dwordx4 lane-request) -> 8 floats
static __device__ __forceinline__ void h8_to_f(const __half* p, float* o)
{
    const float4 raw = *(const float4*)p;
    const __half2* h2 = (const __half2*)&raw;
#pragma unroll
    for (int k = 0; k < 4; k++) {
        const float2 f = __half22float2(h2[k]);
        o[2 * k]     = f.x;
        o[2 * k + 1] = f.y;
    }
}

// bf16 (round-to-nearest-even): fp32 exponent RANGE — safe for 1/denom,
// which reaches ~3e-7 (fp16 min normal is 6.1e-5; R7 failed exactly there)
static __device__ __forceinline__ unsigned short f_to_b(float f)
{
    unsigned int u = __float_as_uint(f);
    u += 0x7FFFu + ((u >> 16) & 1u);
    return (unsigned short)(u >> 16);
}

// load a row of 8 bf16 (16 B, ONE dwordx4 lane-request) -> 8 floats
static __device__ __forceinline__ void b8_to_f(const unsigned short* p, float* o)
{
    const uint4 raw = *(const uint4*)p;
    const unsigned int u[4] = {raw.x, raw.y, raw.z, raw.w};
#pragma unroll
    for (int k = 0; k < 4; k++) {
        o[2 * k]     = __uint_as_float(u[k] << 16);
        o[2 * k + 1] = __uint_as_float(u[k] & 0xFFFF0000u);
    }
}

// ---------------------------------------------------------------------------
// K1: wx = x @ W   (100000x128 @ 128x128, fp32 vector FMA)
//     + fused epilogue: s_src16/s_dst16 (fp16 rows; scores are O(15) so fp16
//     is range-safe; same rounded values feed numerator AND denominator)
// ---------------------------------------------------------------------------
__global__ __launch_bounds__(256) void gemm_s_kernel(
    const float* __restrict__ x, const float* __restrict__ W,
    const float* __restrict__ a, float* __restrict__ wx,
    __half* __restrict__ s_src16, __half* __restrict__ s_dst16)
{
    __shared__ float xs[8][128];   // [k][row] transposed x tile
    __shared__ float Ws[8][128];   // [k][col]

    const int tid = threadIdx.x;
    const int ty  = tid >> 4;      // 0..15  -> row group (8 rows)
    const int tx  = tid & 15;      // 0..15  -> col group (8 cols)
    const int row0 = blockIdx.x * 128;

    float acc[8][8];
#pragma unroll
    for (int i = 0; i < 8; i++)
#pragma unroll
        for (int j = 0; j < 8; j++) acc[i][j] = 0.f;

    const int lrow  = tid >> 1;        // 0..127 row for x staging
    const int khalf = (tid & 1) * 4;   // 0 or 4
    const int wkk   = tid >> 5;        // 0..7 k-row for W staging
    const int wc    = (tid & 31) * 4;  // col*4

    for (int k0 = 0; k0 < IN_F; k0 += 8) {
        float4 xv = make_float4(0.f, 0.f, 0.f, 0.f);
        const int grow = row0 + lrow;
        if (grow < N_NODES)
            xv = *(const float4*)(x + (size_t)grow * IN_F + k0 + khalf);
        const float4 wv = *(const float4*)(W + (size_t)(k0 + wkk) * ATT + wc);

        __syncthreads();   // previous iter's reads done
        xs[khalf + 0][lrow] = xv.x;
        xs[khalf + 1][lrow] = xv.y;
        xs[khalf + 2][lrow] = xv.z;
        xs[khalf + 3][lrow] = xv.w;
        *(float4*)(&Ws[wkk][wc]) = wv;
        __syncthreads();

#pragma unroll
        for (int kk = 0; kk < 8; kk++) {
            float av[8], bv[8];
            *(float4*)(av)     = *(const float4*)(&xs[kk][ty * 8]);
            *(float4*)(av + 4) = *(const float4*)(&xs[kk][ty * 8 + 4]);
            *(float4*)(bv)     = *(const float4*)(&Ws[kk][tx * 8]);
            *(float4*)(bv + 4) = *(const float4*)(&Ws[kk][tx * 8 + 4]);
#pragma unroll
            for (int r = 0; r < 8; r++)
#pragma unroll
                for (int c = 0; c < 8; c++)
                    acc[r][c] = fmaf(av[r], bv[c], acc[r][c]);
        }
    }

    const int koff = (tx & 1) * 8;
    const int head = tx >> 1;
    float a1[8], a2[8];
#pragma unroll
    for (int c = 0; c < 8; c++) {
        a1[c] = a[koff + c];
        a2[c] = a[DK + koff + c];
    }

#pragma unroll
    for (int r = 0; r < 8; r++) {
        const int grow = row0 + ty * 8 + r;
        const bool ok = (grow < N_NODES);
        if (ok) {
            *(float4*)(wx + (size_t)grow * ATT + tx * 8) =
                make_float4(acc[r][0], acc[r][1], acc[r][2], acc[r][3]);
            *(float4*)(wx + (size_t)grow * ATT + tx * 8 + 4) =
                make_float4(acc[r][4], acc[r][5], acc[r][6], acc[r][7]);
        }
        float p1 = 0.f, p2 = 0.f;
#pragma unroll
        for (int c = 0; c < 8; c++) {
            p1 = fmaf(acc[r][c], a1[c], p1);
            p2 = fmaf(acc[r][c], a2[c], p2);
        }
        p1 += __shfl_xor(p1, 1);
        p2 += __shfl_xor(p2, 1);
        if (((tx & 1) == 0) && ok) {
            s_src16[(size_t)grow * HEADS + head] = __float2half_rn(p1);
            s_dst16[(size_t)grow * HEADS + head] = __float2half_rn(p2);
        }
    }
}

// ---------------------------------------------------------------------------
// K2a: per-block histogram of src -> chunk bins. counts[c][b] layout
// ---------------------------------------------------------------------------
__global__ __launch_bounds__(256) void hist_kernel(
    const int* __restrict__ src, int* __restrict__ counts)
{
    __shared__ int h[NBINS];
    const int t = threadIdx.x;
    const int b = blockIdx.x;
    for (int i = t; i < NBINS; i += 256) h[i] = 0;
    __syncthreads();

    const int rb = b * EPB;
    const int re = min(rb + EPB, E_EDGES);
    for (int i = rb + t * 4; i < re; i += 256 * 4) {
        const int4 s4 = *(const int4*)(src + i);
        atomicAdd(&h[s4.x / CHUNK], 1);
        atomicAdd(&h[s4.y / CHUNK], 1);
        atomicAdd(&h[s4.z / CHUNK], 1);
        atomicAdd(&h[s4.w / CHUNK], 1);
    }
    __syncthreads();
    for (int i = t; i < NBINS; i += 256) counts[i * HB + b] = h[i];
}

// ---------------------------------------------------------------------------
// K2b: single-block exclusive prefix scan over counts[NBINS*HB] -> offs
// ---------------------------------------------------------------------------
__global__ __launch_bounds__(1024) void scan_kernel(
    const int* __restrict__ counts, int* __restrict__ offs)
{
    __shared__ int part[1024];
    const int t = threadIdx.x;
    const int per = (NBINS * HB) / 1024;   // 224
    const int base = t * per;

    int sum = 0;
    for (int i = 0; i < per; i++) sum += counts[base + i];
    part[t] = sum;
    __syncthreads();

    for (int off = 1; off < 1024; off <<= 1) {
        int v = 0;
        if (t >= off) v = part[t - off];
        __syncthreads();
        if (t >= off) part[t] += v;
        __syncthreads();
    }

    int run = (t == 0) ? 0 : part[t - 1];
    for (int i = 0; i < per; i++) {
        offs[base + i] = run;
        run += counts[base + i];
    }
}

// ---------------------------------------------------------------------------
// K2c: scatter edges into chunk bins (4-B payload).
//      word = (src - lo) << 17 | dst   (sl < 224 -> 8 bits, dst < 2^17)
// ---------------------------------------------------------------------------
__global__ __launch_bounds__(256) void scatter_kernel(
    const int* __restrict__ src, const int* __restrict__ dst,
    const int* __restrict__ offs, unsigned int* __restrict__ binned)
{
    __shared__ int cur[NBINS];
    const int t = threadIdx.x;
    const int b = blockIdx.x;
    for (int i = t; i < NBINS; i += 256) cur[i] = offs[i * HB + b];
    __syncthreads();

    const int rb = b * EPB;
    const int re = min(rb + EPB, E_EDGES);
    for (int i = rb + t * 4; i < re; i += 256 * 4) {
        const int4 s4 = *(const int4*)(src + i);
        const int4 d4 = *(const int4*)(dst + i);
        const int ss[4] = {s4.x, s4.y, s4.z, s4.w};
        const int dd[4] = {d4.x, d4.y, d4.z, d4.w};
#pragma unroll
        for (int j = 0; j < 4; j++) {
            const int c = ss[j] / CHUNK;
            const int pos = atomicAdd(&cur[c], 1);
            binned[pos] = ((unsigned int)(ss[j] - c * CHUNK) << 17) |
                          (unsigned int)dd[j];
        }
    }
}

// ---------------------------------------------------------------------------
// K2d: per-bin denom pass. Block (c, j): split j of chunk c's bin.
//  R9 experiment: total privatized-slot work (NS*NH) halved; per-edge inner
//  loop identical to R8. LDS 14.4 KB -> all 7 blocks/CU co-resident.
// ---------------------------------------------------------------------------
__global__ __launch_bounds__(256, 8) void denom_binned_kernel(
    const unsigned int* __restrict__ binned, const int* __restrict__ offs,
    const __half* __restrict__ s_src16, const __half* __restrict__ s_dst16,
    float* __restrict__ denoms)   // [NS][NH]
{
    __shared__ float acc[HEADS][CHUNK + 1];   // 7200 B
    __shared__ float ssrc[CHUNK * HEADS];     // 7168 B

    const int t  = threadIdx.x;
    const int c  = blockIdx.x;
    const int j  = blockIdx.y;
    const int lo = c * CHUNK;
    const int hi = min(lo + CHUNK, N_NODES);

    for (int i = t; i < HEADS * (CHUNK + 1); i += 256)
        ((float*)acc)[i] = 0.f;
    {
        // stage + decode: one 16-B row (8 halfs) per node, coalesced
        for (int nd = t; nd < hi - lo; nd += 256) {
            float f[8];
            h8_to_f(s_src16 + (size_t)(lo + nd) * HEADS, f);
            float4* dp = (float4*)(ssrc + nd * HEADS);
            dp[0] = make_float4(f[0], f[1], f[2], f[3]);
            dp[1] = make_float4(f[4], f[5], f[6], f[7]);
        }
    }
    __syncthreads();

    const int start = offs[c * HB];
    const int end   = (c + 1 < NBINS) ? offs[(c + 1) * HB] : E_EDGES;
    const int len   = end - start;
    const int e0 = start + (int)((long long)len * j / NS);
    const int e1 = start + (int)((long long)len * (j + 1) / NS);

    int i = e0 + t;
    bool v0 = i < e1;
    bool v1 = i + 256 < e1;
    unsigned int pw0 = v0 ? binned[i] : 0u;
    unsigned int pw1 = v1 ? binned[i + 256] : 0u;

    while (v0) {
        const unsigned int w0 = pw0;
        const unsigned int w1 = v1 ? pw1 : pw0;   // safe duplicate for tail
        const bool cv1 = v1;

        // prefetch next pair while this pair's gathers are in flight
        i += 512;
        v0 = i < e1;
        v1 = i + 256 < e1;
        if (v0) pw0 = binned[i];
        if (v1) pw1 = binned[i + 256];

        const int sl0 = (int)(w0 >> 17), di0 = (int)(w0 & 0x1FFFFu);
        const int sl1 = (int)(w1 >> 17), di1 = (int)(w1 & 0x1FFFFu);

        // ONE divergent lane-request per edge
        float db0[8], db1[8];
        h8_to_f(s_dst16 + (size_t)di0 * HEADS, db0);
        h8_to_f(s_dst16 + (size_t)di1 * HEADS, db1);

        const float4* qs0 = (const float4*)(ssrc + sl0 * HEADS);
        const float4* qs1 = (const float4*)(ssrc + sl1 * HEADS);
        const float4 xa0 = qs0[0], xa1 = qs0[1];
        const float4 ya0 = qs1[0], ya1 = qs1[1];
        const float sa[8] = {xa0.x, xa0.y, xa0.z, xa0.w, xa1.x, xa1.y, xa1.z, xa1.w};
        const float sb[8] = {ya0.x, ya0.y, ya0.z, ya0.w, ya1.x, ya1.y, ya1.z, ya1.w};

#pragma unroll
        for (int h = 0; h < 8; h++) {
            float v = sa[h] + db0[h]; v = v > 0.f ? v : SLOPE * v;
            atomicAdd(&acc[h][sl0], __expf(v));
        }
        if (cv1) {
#pragma unroll
            for (int h = 0; h < 8; h++) {
                float v = sb[h] + db1[h]; v = v > 0.f ? v : SLOPE * v;
                atomicAdd(&acc[h][sl1], __expf(v));
            }
        }
    }
    __syncthreads();

    // flush: coalesced float4 writes into this split's private copy
    float* outp = denoms + (size_t)j * NH + (size_t)lo * HEADS;
    for (int nd = t; nd < hi - lo; nd += 256) {
        const float4 o0 = make_float4(acc[0][nd], acc[1][nd], acc[2][nd], acc[3][nd]);
        const float4 o1 = make_float4(acc[4][nd], acc[5][nd], acc[6][nd], acc[7][nd]);
        *(float4*)(outp + (size_t)nd * 8)     = o0;
        *(float4*)(outp + (size_t)nd * 8 + 4) = o1;
    }
}

// ---------------------------------------------------------------------------
// K2e: rdb[i] = bf16( 1 / sum_c denoms[c][i] )  — bf16 keeps fp32 RANGE
// ---------------------------------------------------------------------------
__global__ __launch_bounds__(256) void reduce_recip_kernel(
    const float* __restrict__ denoms, unsigned short* __restrict__ rdb)
{
    const int i = blockIdx.x * 256 + threadIdx.x;
    if (i >= NH) return;
    float s = 0.f;
#pragma unroll
    for (int c = 0; c < NS; c++) s += denoms[(size_t)c * NH + i];
    rdb[i] = f_to_b(__frcp_rn(s));
}

// ---------------------------------------------------------------------------
// K3: e-order normalize, 2 edges/thread.
//  Per edge: s_src16 row (1 lane-request) + s_dst16 row (1) + rdb row (1).
//  att write fully coalesced. Same fp16 scores as the denom pass.
// ---------------------------------------------------------------------------
__global__ __launch_bounds__(256) void norm_e_kernel(
    const int* __restrict__ src, const int* __restrict__ dst,
    const __half* __restrict__ s_src16, const __half* __restrict__ s_dst16,
    const unsigned short* __restrict__ rdb, float* __restrict__ att)
{
    const int e0 = (blockIdx.x * 256 + threadIdx.x) * 2;
    if (e0 >= E_EDGES) return;
    const int2 sp = *(const int2*)(src + e0);
    const int2 dp = *(const int2*)(dst + e0);

    // issue all divergent loads first (6 lane-requests in flight)
    float sa[8], sb[8], d0[8], d1[8], r0[8], r1[8];
    h8_to_f(s_src16 + (size_t)sp.x * HEADS, sa);
    h8_to_f(s_src16 + (size_t)sp.y * HEADS, sb);
    h8_to_f(s_dst16 + (size_t)dp.x * HEADS, d0);
    h8_to_f(s_dst16 + (size_t)dp.y * HEADS, d1);
    b8_to_f(rdb + (size_t)sp.x * HEADS, r0);
    b8_to_f(rdb + (size_t)sp.y * HEADS, r1);

    float o0[8], o1[8];
#pragma unroll
    for (int h = 0; h < 8; h++) {
        float v = sa[h] + d0[h]; v = v > 0.f ? v : SLOPE * v;
        o0[h] = __expf(v) * r0[h];
        float u = sb[h] + d1[h]; u = u > 0.f ? u : SLOPE * u;
        o1[h] = __expf(u) * r1[h];
    }

    float4* pa = (float4*)(att + (size_t)e0 * HEADS);
    pa[0] = make_float4(o0[0], o0[1], o0[2], o0[3]);
    pa[1] = make_float4(o0[4], o0[5], o0[6], o0[7]);
    pa[2] = make_float4(o1[0], o1[1], o1[2], o1[3]);
    pa[3] = make_float4(o1[4], o1[5], o1[6], o1[7]);
}

extern "C" void kernel_launch(void* const* d_in, const int* in_sizes, int n_in,
                              void* d_out, int out_size, void* d_ws, size_t ws_size,
                              hipStream_t stream)
{
    const float* x    = (const float*)d_in[0];
    const int*   edge = (const int*)d_in[1];
    const float* W    = (const float*)d_in[2];
    const float* a    = (const float*)d_in[3];

    float* out = (float*)d_out;
    float* att = out;                                 // (E, HEADS)
    float* wx  = out + (size_t)E_EDGES * HEADS;       // (N, ATT)

    float*  ws      = (float*)d_ws;
    float*  denoms  = ws;                             // NS*NH floats (12.8 MB)
    __half* s_src16 = (__half*)(denoms + (size_t)NS * NH);   // NH halfs (1.6 MB)
    __half* s_dst16 = s_src16 + (size_t)NH;                  // NH halfs (1.6 MB)
    unsigned short* rdb = (unsigned short*)(s_dst16 + (size_t)NH); // NH (1.6 MB)
    int*    counts  = (int*)(rdb + (size_t)NH);       // NBINS*HB ints (917 KB)
    int*    offs    = counts + (size_t)NBINS * HB;    // NBINS*HB ints (917 KB)
    unsigned int* binned = (unsigned int*)(offs + (size_t)NBINS * HB); // E uints

    const int* src = edge;                 // edge[0][0][:]
    const int* dst = edge + E_EDGES;       // edge[0][1][:]

    const int gemm_blocks = (N_NODES + 127) / 128;    // 782
    gemm_s_kernel<<<gemm_blocks, 256, 0, stream>>>(x, W, a, wx, s_src16, s_dst16);

    hist_kernel<<<HB, 256, 0, stream>>>(src, counts);
    scan_kernel<<<1, 1024, 0, stream>>>(counts, offs);
    scatter_kernel<<<HB, 256, 0, stream>>>(src, dst, offs, binned);

    dim3 bgrid(NBINS, NS);                            // 448 x 4 = 1792 blocks
    denom_binned_kernel<<<bgrid, 256, 0, stream>>>(binned, offs, s_src16, s_dst16, denoms);

    const int nblocks = (NH + 255) / 256;
    reduce_recip_kernel<<<nblocks, 256, 0, stream>>>(denoms, rdb);

    const int eblocks = (E_EDGES / 2 + 255) / 256;    // 6250
    norm_e_kernel<<<eblocks, 256, 0, stream>>>(src, dst, s_src16, s_dst16,
                                               rdb, att);
}

// Round 10
// 533.197 us; speedup vs baseline: 1.0854x; 1.0854x over previous
//
#include <hip/hip_runtime.h>
#include <hip/hip_fp16.h>

#define N_NODES 100000
#define E_EDGES 3200000
#define IN_F 128
#define ATT 128
#define HEADS 8
#define DK 16
#define SLOPE 0.2f
#define NH (N_NODES * HEADS)   // 800000

// Binning parameters (R10: NS=1 — 448 fat blocks, 28 edge-iterations each;
// per-block fixed cost amortized 8x vs the constant-78us/block R2-R9 shape)
#define CHUNK 224
#define NBINS 448                 // 448*224 = 100352 >= N
#define HB 256                    // hist/scatter blocks (R9's 512 doubled scan work)
#define EPB 12544                 // edges per hist/scatter block (256*12544 >= E)
#define DTH 512                   // denom block threads

// load a row of 8 halfs (16 B, ONE dwordx4 lane-request) -> 8 floats
static __device__ __forceinline__ void h8_to_f(const __half* p, float* o)
{
    const float4 raw = *(const float4*)p;
    const __half2* h2 = (const __half2*)&raw;
#pragma unroll
    for (int k = 0; k < 4; k++) {
        const float2 f = __half22float2(h2[k]);
        o[2 * k]     = f.x;
        o[2 * k + 1] = f.y;
    }
}

// bf16 (round-to-nearest-even): fp32 exponent RANGE — safe for 1/denom,
// which reaches ~3e-7 (fp16 min normal is 6.1e-5; R7 failed exactly there)
static __device__ __forceinline__ unsigned int f_to_b(float f)
{
    unsigned int u = __float_as_uint(f);
    u += 0x7FFFu + ((u >> 16) & 1u);
    return u >> 16;
}

// decode 8 bf16 packed in a uint4 -> 8 floats
static __device__ __forceinline__ void b8_dec(const uint4 raw, float* o)
{
    const unsigned int u[4] = {raw.x, raw.y, raw.z, raw.w};
#pragma unroll
    for (int k = 0; k < 4; k++) {
        o[2 * k]     = __uint_as_float(u[k] << 16);
        o[2 * k + 1] = __uint_as_float(u[k] & 0xFFFF0000u);
    }
}

// combo table: one 32-B row per node, 64-B-line aligned in pairs:
//   bytes [0,16)  : s_src scores, 8 x fp16   (written by gemm epilogue)
//   bytes [16,32) : 1/denom,      8 x bf16   (written by denom flush)
// norm reads both halves of one line -> 1 divergent line-event for src data.

// ---------------------------------------------------------------------------
// K1: wx = x @ W   (100000x128 @ 128x128, fp32 vector FMA)
//     + fused epilogue: combo[n].s_src (fp16) and s_dst16[n][h] (fp16)
// ---------------------------------------------------------------------------
__global__ __launch_bounds__(256) void gemm_s_kernel(
    const float* __restrict__ x, const float* __restrict__ W,
    const float* __restrict__ a, float* __restrict__ wx,
    __half* __restrict__ combo, __half* __restrict__ s_dst16)
{
    __shared__ float xs[8][128];   // [k][row] transposed x tile
    __shared__ float Ws[8][128];   // [k][col]

    const int tid = threadIdx.x;
    const int ty  = tid >> 4;      // 0..15  -> row group (8 rows)
    const int tx  = tid & 15;      // 0..15  -> col group (8 cols)
    const int row0 = blockIdx.x * 128;

    float acc[8][8];
#pragma unroll
    for (int i = 0; i < 8; i++)
#pragma unroll
        for (int j = 0; j < 8; j++) acc[i][j] = 0.f;

    const int lrow  = tid >> 1;        // 0..127 row for x staging
    const int khalf = (tid & 1) * 4;   // 0 or 4
    const int wkk   = tid >> 5;        // 0..7 k-row for W staging
    const int wc    = (tid & 31) * 4;  // col*4

    for (int k0 = 0; k0 < IN_F; k0 += 8) {
        float4 xv = make_float4(0.f, 0.f, 0.f, 0.f);
        const int grow = row0 + lrow;
        if (grow < N_NODES)
            xv = *(const float4*)(x + (size_t)grow * IN_F + k0 + khalf);
        const float4 wv = *(const float4*)(W + (size_t)(k0 + wkk) * ATT + wc);

        __syncthreads();   // previous iter's reads done
        xs[khalf + 0][lrow] = xv.x;
        xs[khalf + 1][lrow] = xv.y;
        xs[khalf + 2][lrow] = xv.z;
        xs[khalf + 3][lrow] = xv.w;
        *(float4*)(&Ws[wkk][wc]) = wv;
        __syncthreads();

#pragma unroll
        for (int kk = 0; kk < 8; kk++) {
            float av[8], bv[8];
            *(float4*)(av)     = *(const float4*)(&xs[kk][ty * 8]);
            *(float4*)(av + 4) = *(const float4*)(&xs[kk][ty * 8 + 4]);
            *(float4*)(bv)     = *(const float4*)(&Ws[kk][tx * 8]);
            *(float4*)(bv + 4) = *(const float4*)(&Ws[kk][tx * 8 + 4]);
#pragma unroll
            for (int r = 0; r < 8; r++)
#pragma unroll
                for (int c = 0; c < 8; c++)
                    acc[r][c] = fmaf(av[r], bv[c], acc[r][c]);
        }
    }

    const int koff = (tx & 1) * 8;
    const int head = tx >> 1;
    float a1[8], a2[8];
#pragma unroll
    for (int c = 0; c < 8; c++) {
        a1[c] = a[koff + c];
        a2[c] = a[DK + koff + c];
    }

#pragma unroll
    for (int r = 0; r < 8; r++) {
        const int grow = row0 + ty * 8 + r;
        const bool ok = (grow < N_NODES);
        if (ok) {
            *(float4*)(wx + (size_t)grow * ATT + tx * 8) =
                make_float4(acc[r][0], acc[r][1], acc[r][2], acc[r][3]);
            *(float4*)(wx + (size_t)grow * ATT + tx * 8 + 4) =
                make_float4(acc[r][4], acc[r][5], acc[r][6], acc[r][7]);
        }
        float p1 = 0.f, p2 = 0.f;
#pragma unroll
        for (int c = 0; c < 8; c++) {
            p1 = fmaf(acc[r][c], a1[c], p1);
            p2 = fmaf(acc[r][c], a2[c], p2);
        }
        p1 += __shfl_xor(p1, 1);
        p2 += __shfl_xor(p2, 1);
        if (((tx & 1) == 0) && ok) {
            combo[(size_t)grow * 16 + head]      = __float2half_rn(p1);
            s_dst16[(size_t)grow * HEADS + head] = __float2half_rn(p2);
        }
    }
}

// ---------------------------------------------------------------------------
// K2a: per-block histogram of src -> chunk bins. counts[c][b] layout
// ---------------------------------------------------------------------------
__global__ __launch_bounds__(256) void hist_kernel(
    const int* __restrict__ src, int* __restrict__ counts)
{
    __shared__ int h[NBINS];
    const int t = threadIdx.x;
    const int b = blockIdx.x;
    for (int i = t; i < NBINS; i += 256) h[i] = 0;
    __syncthreads();

    const int rb = b * EPB;
    const int re = min(rb + EPB, E_EDGES);
    for (int i = rb + t * 4; i < re; i += 256 * 4) {
        const int4 s4 = *(const int4*)(src + i);
        atomicAdd(&h[s4.x / CHUNK], 1);
        atomicAdd(&h[s4.y / CHUNK], 1);
        atomicAdd(&h[s4.z / CHUNK], 1);
        atomicAdd(&h[s4.w / CHUNK], 1);
    }
    __syncthreads();
    for (int i = t; i < NBINS; i += 256) counts[i * HB + b] = h[i];
}

// ---------------------------------------------------------------------------
// K2b: single-block exclusive prefix scan over counts[NBINS*HB] -> offs
// ---------------------------------------------------------------------------
__global__ __launch_bounds__(1024) void scan_kernel(
    const int* __restrict__ counts, int* __restrict__ offs)
{
    __shared__ int part[1024];
    const int t = threadIdx.x;
    const int per = (NBINS * HB) / 1024;   // 112
    const int base = t * per;

    int sum = 0;
    for (int i = 0; i < per; i++) sum += counts[base + i];
    part[t] = sum;
    __syncthreads();

    for (int off = 1; off < 1024; off <<= 1) {
        int v = 0;
        if (t >= off) v = part[t - off];
        __syncthreads();
        if (t >= off) part[t] += v;
        __syncthreads();
    }

    int run = (t == 0) ? 0 : part[t - 1];
    for (int i = 0; i < per; i++) {
        offs[base + i] = run;
        run += counts[base + i];
    }
}

// ---------------------------------------------------------------------------
// K2c: scatter edges into chunk bins (4-B payload).
//      word = (src - lo) << 17 | dst   (sl < 224 -> 8 bits, dst < 2^17)
// ---------------------------------------------------------------------------
__global__ __launch_bounds__(256) void scatter_kernel(
    const int* __restrict__ src, const int* __restrict__ dst,
    const int* __restrict__ offs, unsigned int* __restrict__ binned)
{
    __shared__ int cur[NBINS];
    const int t = threadIdx.x;
    const int b = blockIdx.x;
    for (int i = t; i < NBINS; i += 256) cur[i] = offs[i * HB + b];
    __syncthreads();

    const int rb = b * EPB;
    const int re = min(rb + EPB, E_EDGES);
    for (int i = rb + t * 4; i < re; i += 256 * 4) {
        const int4 s4 = *(const int4*)(src + i);
        const int4 d4 = *(const int4*)(dst + i);
        const int ss[4] = {s4.x, s4.y, s4.z, s4.w};
        const int dd[4] = {d4.x, d4.y, d4.z, d4.w};
#pragma unroll
        for (int j = 0; j < 4; j++) {
            const int c = ss[j] / CHUNK;
            const int pos = atomicAdd(&cur[c], 1);
            binned[pos] = ((unsigned int)(ss[j] - c * CHUNK) << 17) |
                          (unsigned int)dd[j];
        }
    }
}

// ---------------------------------------------------------------------------
// K2d: per-bin denom pass, NS=1. One 512-thread block owns bin c entirely:
//  ~7142 edges -> 7 pipeline iterations (vs 3.5 at 1792 blocks) — tests the
//  per-block-fixed-cost theory (R2-R9: constant ~78us/block at every other
//  parameter). Flush folds 1/denom + bf16 pack, writing combo[n].rdenom
//  directly — no private copies, no reduce kernel.
// ---------------------------------------------------------------------------
__global__ __launch_bounds__(DTH) void denom_binned_kernel(
    const unsigned int* __restrict__ binned, const int* __restrict__ offs,
    __half* __restrict__ combo, const __half* __restrict__ s_dst16)
{
    __shared__ float acc[HEADS][CHUNK + 1];   // 7200 B
    __shared__ float ssrc[CHUNK * HEADS];     // 7168 B

    const int t  = threadIdx.x;
    const int c  = blockIdx.x;
    const int lo = c * CHUNK;
    const int hi = min(lo + CHUNK, N_NODES);

    for (int i = t; i < HEADS * (CHUNK + 1); i += DTH)
        ((float*)acc)[i] = 0.f;
    {
        // stage + decode s_src half of combo rows (16 B per node)
        for (int nd = t; nd < hi - lo; nd += DTH) {
            float f[8];
            h8_to_f(combo + (size_t)(lo + nd) * 16, f);
            float4* dp = (float4*)(ssrc + nd * HEADS);
            dp[0] = make_float4(f[0], f[1], f[2], f[3]);
            dp[1] = make_float4(f[4], f[5], f[6], f[7]);
        }
    }
    __syncthreads();

    const int e0 = offs[c * HB];
    const int e1 = (c + 1 < NBINS) ? offs[(c + 1) * HB] : E_EDGES;

    int i = e0 + t;
    bool v0 = i < e1;
    bool v1 = i + DTH < e1;
    unsigned int pw0 = v0 ? binned[i] : 0u;
    unsigned int pw1 = v1 ? binned[i + DTH] : 0u;

    while (v0) {
        const unsigned int w0 = pw0;
        const unsigned int w1 = v1 ? pw1 : pw0;   // safe duplicate for tail
        const bool cv1 = v1;

        // prefetch next pair while this pair's gathers are in flight
        i += 2 * DTH;
        v0 = i < e1;
        v1 = i + DTH < e1;
        if (v0) pw0 = binned[i];
        if (v1) pw1 = binned[i + DTH];

        const int sl0 = (int)(w0 >> 17), di0 = (int)(w0 & 0x1FFFFu);
        const int sl1 = (int)(w1 >> 17), di1 = (int)(w1 & 0x1FFFFu);

        // ONE divergent lane-request per edge
        float db0[8], db1[8];
        h8_to_f(s_dst16 + (size_t)di0 * HEADS, db0);
        h8_to_f(s_dst16 + (size_t)di1 * HEADS, db1);

        const float4* qs0 = (const float4*)(ssrc + sl0 * HEADS);
        const float4* qs1 = (const float4*)(ssrc + sl1 * HEADS);
        const float4 xa0 = qs0[0], xa1 = qs0[1];
        const float4 ya0 = qs1[0], ya1 = qs1[1];
        const float sa[8] = {xa0.x, xa0.y, xa0.z, xa0.w, xa1.x, xa1.y, xa1.z, xa1.w};
        const float sb[8] = {ya0.x, ya0.y, ya0.z, ya0.w, ya1.x, ya1.y, ya1.z, ya1.w};

#pragma unroll
        for (int h = 0; h < 8; h++) {
            float v = sa[h] + db0[h]; v = v > 0.f ? v : SLOPE * v;
            atomicAdd(&acc[h][sl0], __expf(v));
        }
        if (cv1) {
#pragma unroll
            for (int h = 0; h < 8; h++) {
                float v = sb[h] + db1[h]; v = v > 0.f ? v : SLOPE * v;
                atomicAdd(&acc[h][sl1], __expf(v));
            }
        }
    }
    __syncthreads();

    // flush: rdenom = bf16(1/acc) packed into combo[n] bytes [16,32)
    for (int nd = t; nd < hi - lo; nd += DTH) {
        unsigned int u[4];
#pragma unroll
        for (int k = 0; k < 4; k++) {
            const unsigned int b0 = f_to_b(__frcp_rn(acc[2 * k][nd]));
            const unsigned int b1 = f_to_b(__frcp_rn(acc[2 * k + 1][nd]));
            u[k] = b0 | (b1 << 16);
        }
        *(uint4*)(combo + (size_t)(lo + nd) * 16 + 8) =
            make_uint4(u[0], u[1], u[2], u[3]);
    }
}

// ---------------------------------------------------------------------------
// K3: e-order normalize, 2 edges/thread.
//  Per edge: combo[src] 32-B row (s_src fp16 + rdenom bf16, ONE 64-B line,
//  2 requests) + s_dst16[dst] row (1 request) = 2 divergent line-events.
//  att write fully coalesced. Same fp16 scores as the denom pass.
// ---------------------------------------------------------------------------
__global__ __launch_bounds__(256) void norm_e_kernel(
    const int* __restrict__ src, const int* __restrict__ dst,
    const __half* __restrict__ combo, const __half* __restrict__ s_dst16,
    float* __restrict__ att)
{
    const int e0 = (blockIdx.x * 256 + threadIdx.x) * 2;
    if (e0 >= E_EDGES) return;
    const int2 sp = *(const int2*)(src + e0);
    const int2 dp = *(const int2*)(dst + e0);

    // issue all divergent loads first
    const uint4* c0 = (const uint4*)(combo + (size_t)sp.x * 16);
    const uint4* c1 = (const uint4*)(combo + (size_t)sp.y * 16);
    const uint4 c0s = c0[0], c0r = c0[1];
    const uint4 c1s = c1[0], c1r = c1[1];
    float d0[8], d1[8];
    h8_to_f(s_dst16 + (size_t)dp.x * HEADS, d0);
    h8_to_f(s_dst16 + (size_t)dp.y * HEADS, d1);

    float sa[8], sb[8], r0[8], r1[8];
    h8_to_f((const __half*)&c0s, sa);
    h8_to_f((const __half*)&c1s, sb);
    b8_dec(c0r, r0);
    b8_dec(c1r, r1);

    float o0[8], o1[8];
#pragma unroll
    for (int h = 0; h < 8; h++) {
        float v = sa[h] + d0[h]; v = v > 0.f ? v : SLOPE * v;
        o0[h] = __expf(v) * r0[h];
        float u = sb[h] + d1[h]; u = u > 0.f ? u : SLOPE * u;
        o1[h] = __expf(u) * r1[h];
    }

    float4* pa = (float4*)(att + (size_t)e0 * HEADS);
    pa[0] = make_float4(o0[0], o0[1], o0[2], o0[3]);
    pa[1] = make_float4(o0[4], o0[5], o0[6], o0[7]);
    pa[2] = make_float4(o1[0], o1[1], o1[2], o1[3]);
    pa[3] = make_float4(o1[4], o1[5], o1[6], o1[7]);
}

extern "C" void kernel_launch(void* const* d_in, const int* in_sizes, int n_in,
                              void* d_out, int out_size, void* d_ws, size_t ws_size,
                              hipStream_t stream)
{
    const float* x    = (const float*)d_in[0];
    const int*   edge = (const int*)d_in[1];
    const float* W    = (const float*)d_in[2];
    const float* a    = (const float*)d_in[3];

    float* out = (float*)d_out;
    float* att = out;                                 // (E, HEADS)
    float* wx  = out + (size_t)E_EDGES * HEADS;       // (N, ATT)

    __half* combo   = (__half*)d_ws;                  // N * 16 halfs (3.2 MB)
    __half* s_dst16 = combo + (size_t)N_NODES * 16;   // NH halfs (1.6 MB)
    int*    counts  = (int*)(s_dst16 + (size_t)NH);   // NBINS*HB ints (458 KB)
    int*    offs    = counts + (size_t)NBINS * HB;    // NBINS*HB ints (458 KB)
    unsigned int* binned = (unsigned int*)(offs + (size_t)NBINS * HB); // E uints

    const int* src = edge;                 // edge[0][0][:]
    const int* dst = edge + E_EDGES;       // edge[0][1][:]

    const int gemm_blocks = (N_NODES + 127) / 128;    // 782
    gemm_s_kernel<<<gemm_blocks, 256, 0, stream>>>(x, W, a, wx, combo, s_dst16);

    hist_kernel<<<HB, 256, 0, stream>>>(src, counts);
    scan_kernel<<<1, 1024, 0, stream>>>(counts, offs);
    scatter_kernel<<<HB, 256, 0, stream>>>(src, dst, offs, binned);

    denom_binned_kernel<<<NBINS, DTH, 0, stream>>>(binned, offs, combo, s_dst16);

    const int eblocks = (E_EDGES / 2 + 255) / 256;    // 6250
    norm_e_kernel<<<eblocks, 256, 0, stream>>>(src, dst, combo, s_dst16, att);
}